// Round 2
// baseline (211.727 us; speedup 1.0000x reference)
//
#include <hip/hip_runtime.h>
#include <math.h>

// GRU: B=65536, T=9, I=57, H=2, O=1.
// R4: memory-path replacement experiment. Drops ALL LDS / global_load_lds /
// __syncthreads machinery (shared by R1/R2/R3, all ~212us). One thread per
// batch element; its 513-float row is contiguous in global memory, so every
// load is an offset-immediate global_load_dword from a single per-lane base.
// Register double-buffer (xa/xb, statically indexed) prefetches timestep t+1
// under timestep t's compute; no barriers -> no convoy, no vmcnt(0) drains.
// Weight access keeps R2's proven gate-outer structure (<=57 live uniforms
// per gate; t-loop kept rolled) to avoid R1's SGPR-overflow reload collapse.
//
// In-flight bytes/CU = 4 waves x 57 loads x 256B ~= 58 KB >> ~9 KB needed to
// saturate HBM; every 64B line fully consumed via L1/L2 (no strided-chunk
// edge overfetch). Floor: 134.5 MB read ~= 21 us.

#define T_STEPS 9
#define I_DIM   57
#define ROW_F   513  // T*I floats per batch element (contiguous)

__device__ __forceinline__ float sigm(float x) {
    return 1.0f / (1.0f + __expf(-x));
}
__device__ __forceinline__ float tanh_fast(float x) {
    x = fminf(fmaxf(x, -15.0f), 15.0f);
    float e = __expf(2.0f * x);
    return (e - 1.0f) / (e + 1.0f);
}

__global__ __launch_bounds__(64, 1) void gru_kernel(
    const float* __restrict__ x,    // [B, T, I]
    const float* __restrict__ Wih,  // [6, 57]
    const float* __restrict__ Whh,  // [6, 2]
    const float* __restrict__ bih,  // [6]
    const float* __restrict__ bhh,  // [6]
    const float* __restrict__ fcw,  // [1, 2]
    const float* __restrict__ fcb,  // [1]
    float* __restrict__ out)        // [B, 1]
{
    const int lane = threadIdx.x;
    const int b    = blockIdx.x * 64 + lane;
    const float* __restrict__ row = x + (size_t)b * ROW_F;

    // Small uniform params -> SGPRs.
    const float b0 = bih[0], b1 = bih[1], b2 = bih[2],
                b3 = bih[3], b4 = bih[4], b5 = bih[5];
    const float c0 = bhh[0], c1 = bhh[1], c2 = bhh[2],
                c3 = bhh[3], c4 = bhh[4], c5 = bhh[5];
    const float w00 = Whh[0],  w01 = Whh[1];   // gate r0
    const float w10 = Whh[2],  w11 = Whh[3];   // gate r1
    const float w20 = Whh[4],  w21 = Whh[5];   // gate z0
    const float w30 = Whh[6],  w31 = Whh[7];   // gate z1
    const float w40 = Whh[8],  w41 = Whh[9];   // gate n0
    const float w50 = Whh[10], w51 = Whh[11];  // gate n1

    float h0 = 0.0f, h1 = 0.0f;
    float xa[I_DIM], xb[I_DIM];

    // Load one timestep's 57 floats into a register buffer. p is the
    // timestep base; all 57 loads fold to offset-immediates (<= 227B).
    auto load_ts = [&](float (&d)[I_DIM], const float* p) {
#pragma unroll
        for (int i = 0; i < I_DIM; ++i) d[i] = p[i];
    };

    // One GRU step from a register-resident x-row. Gate-outer dots with
    // dual accumulators (chain depth ~29 ~= issue rate); <=57 uniform Wih
    // values live per gate -> scalar-cache batched s_loads, no reg blowup.
    auto step = [&](const float (&xr)[I_DIM]) {
        float aR0 = b0, aR1 = 0.0f;
        {
            const float* wg = Wih + 0 * I_DIM;
#pragma unroll
            for (int i = 0; i < I_DIM - 1; i += 2) {
                aR0 = fmaf(xr[i],     wg[i],     aR0);
                aR1 = fmaf(xr[i + 1], wg[i + 1], aR1);
            }
            aR0 = fmaf(xr[I_DIM - 1], wg[I_DIM - 1], aR0);
        }
        float aS0 = b1, aS1 = 0.0f;
        {
            const float* wg = Wih + 1 * I_DIM;
#pragma unroll
            for (int i = 0; i < I_DIM - 1; i += 2) {
                aS0 = fmaf(xr[i],     wg[i],     aS0);
                aS1 = fmaf(xr[i + 1], wg[i + 1], aS1);
            }
            aS0 = fmaf(xr[I_DIM - 1], wg[I_DIM - 1], aS0);
        }
        float aZ0 = b2, aZ1 = 0.0f;
        {
            const float* wg = Wih + 2 * I_DIM;
#pragma unroll
            for (int i = 0; i < I_DIM - 1; i += 2) {
                aZ0 = fmaf(xr[i],     wg[i],     aZ0);
                aZ1 = fmaf(xr[i + 1], wg[i + 1], aZ1);
            }
            aZ0 = fmaf(xr[I_DIM - 1], wg[I_DIM - 1], aZ0);
        }
        float aY0 = b3, aY1 = 0.0f;
        {
            const float* wg = Wih + 3 * I_DIM;
#pragma unroll
            for (int i = 0; i < I_DIM - 1; i += 2) {
                aY0 = fmaf(xr[i],     wg[i],     aY0);
                aY1 = fmaf(xr[i + 1], wg[i + 1], aY1);
            }
            aY0 = fmaf(xr[I_DIM - 1], wg[I_DIM - 1], aY0);
        }
        float aN0 = b4, aN1 = 0.0f;
        {
            const float* wg = Wih + 4 * I_DIM;
#pragma unroll
            for (int i = 0; i < I_DIM - 1; i += 2) {
                aN0 = fmaf(xr[i],     wg[i],     aN0);
                aN1 = fmaf(xr[i + 1], wg[i + 1], aN1);
            }
            aN0 = fmaf(xr[I_DIM - 1], wg[I_DIM - 1], aN0);
        }
        float aM0 = b5, aM1 = 0.0f;
        {
            const float* wg = Wih + 5 * I_DIM;
#pragma unroll
            for (int i = 0; i < I_DIM - 1; i += 2) {
                aM0 = fmaf(xr[i],     wg[i],     aM0);
                aM1 = fmaf(xr[i + 1], wg[i + 1], aM1);
            }
            aM0 = fmaf(xr[I_DIM - 1], wg[I_DIM - 1], aM0);
        }

        const float gR = c0 + w00 * h0 + w01 * h1;
        const float gS = c1 + w10 * h0 + w11 * h1;
        const float gZ = c2 + w20 * h0 + w21 * h1;
        const float gY = c3 + w30 * h0 + w31 * h1;
        const float gN = c4 + w40 * h0 + w41 * h1;
        const float gM = c5 + w50 * h0 + w51 * h1;

        const float r0 = sigm((aR0 + aR1) + gR);
        const float r1 = sigm((aS0 + aS1) + gS);
        const float z0 = sigm((aZ0 + aZ1) + gZ);
        const float z1 = sigm((aY0 + aY1) + gY);
        const float n0 = tanh_fast((aN0 + aN1) + r0 * gN);
        const float n1 = tanh_fast((aM0 + aM1) + r1 * gM);
        h0 = (1.0f - z0) * n0 + z0 * h0;
        h1 = (1.0f - z1) * n1 + z1 * h1;
    };

    // Software pipeline, depth ~1.5 timesteps: loads for t+1 (and t+2) are
    // issued before the compute that consumes t (and t+1). T=9 (odd):
    // xa holds even timesteps, xb odd; epilogue computes t=8 from xa.
    load_ts(xa, row);                       // t=0
    const float* p = row;
#pragma unroll 1
    for (int t = 0; t < T_STEPS - 1; t += 2) {
        load_ts(xb, p + I_DIM);             // t+1
        step(xa);                           // t
        load_ts(xa, p + 2 * I_DIM);         // t+2 (t+2 <= 8 for all iters)
        step(xb);                           // t+1
        p += 2 * I_DIM;
    }
    step(xa);                               // t=8

    out[b] = fcw[0] * h0 + fcw[1] * h1 + fcb[0];
}

extern "C" void kernel_launch(void* const* d_in, const int* in_sizes, int n_in,
                              void* d_out, int out_size, void* d_ws, size_t ws_size,
                              hipStream_t stream) {
    const float* x   = (const float*)d_in[0];
    const float* Wih = (const float*)d_in[1];
    const float* Whh = (const float*)d_in[2];
    const float* bih = (const float*)d_in[3];
    const float* bhh = (const float*)d_in[4];
    const float* fcw = (const float*)d_in[5];
    const float* fcb = (const float*)d_in[6];
    float* out = (float*)d_out;

    gru_kernel<<<dim3(1024), dim3(64), 0, stream>>>(
        x, Wih, Whh, bih, bhh, fcw, fcb, out);
}